// Round 3
// baseline (511.323 us; speedup 1.0000x reference)
//
#include <hip/hip_runtime.h>
#include <math.h>

// Problem constants: B=1024, T=256, D=128, H=64, 4H=256
constexpr int B_ = 1024;
constexpr int T_ = 256;
constexpr int D_ = 128;
constexpr int H_ = 64;
constexpr int G_ = 4 * H_;        // 256 gate rows
constexpr int M_ = B_ * T_;

typedef short  v8s  __attribute__((ext_vector_type(8)));   // 8 bf16 (4 VGPRs)
typedef float  v4f  __attribute__((ext_vector_type(4)));   // MFMA acc

__device__ __forceinline__ float sigmoidf_(float x) {
    return 1.0f / (1.0f + __expf(-x));
}
// tanh(x) = 2*sigmoid(2x) - 1 ; overflow-safe at both ends, 5 instrs
__device__ __forceinline__ float tanhf_(float x) {
    return fmaf(2.0f, 1.0f / (1.0f + __expf(-2.0f * x)), -1.0f);
}
__device__ __forceinline__ unsigned short f2bf(float f) {   // RNE f32->bf16
    unsigned u = __float_as_uint(f);
    u = (u + 0x7fffu + ((u >> 16) & 1u)) >> 16;
    return (unsigned short)u;
}
__device__ __forceinline__ float bf2f(unsigned short s) {
    return __uint_as_float(((unsigned)s) << 16);
}
__device__ __forceinline__ v8s pack8(float4 a, float4 b) {
    v8s r;
    r[0] = (short)f2bf(a.x); r[1] = (short)f2bf(a.y);
    r[2] = (short)f2bf(a.z); r[3] = (short)f2bf(a.w);
    r[4] = (short)f2bf(b.x); r[5] = (short)f2bf(b.y);
    r[6] = (short)f2bf(b.z); r[7] = (short)f2bf(b.w);
    return r;
}

// ---------------------------------------------------------------------------
// Phase 1 (transposed): xp^T tile = W_ih @ x^T + bias, stored bf16 in the
// exact per-lane fragment order phase 2 consumes: xp[t][bg][gt][lane].{r0..r3}
//   t  = timestep, bg = batch>>4, gt = gatecol>>4, lane = q*16+ml,
//   r  = packed reg index; element = (gate = gt*16+q*4+r, batch = bg*16+ml).
// Grid: 4096 blocks = 256 t x 16 batch-blocks of 64. Block = 256 thr.
// Wave w computes gate m-tiles {4w..4w+3} (A = W_ih rows in regs, K=128),
// x staged once to LDS as bf16 (x read exactly ONCE from HBM chip-wide).
// ---------------------------------------------------------------------------
__global__ __launch_bounds__(256, 1)
void xprojT_kernel(const float* __restrict__ x,       // [B,T,D]
                   const float* __restrict__ W_ih,    // [256,128]
                   const float* __restrict__ b_ih,    // [256]
                   const float* __restrict__ b_hh,    // [256]
                   ushort4* __restrict__ xp)          // [256][64][16][64]
{
    const int t    = blockIdx.x >> 4;
    const int bbl  = blockIdx.x & 15;
    const int b0   = bbl * 64;
    const int tid  = threadIdx.x;
    const int w    = tid >> 6;
    const int lane = tid & 63;
    const int q    = lane >> 4;
    const int ml   = lane & 15;

    __shared__ __align__(16) unsigned short Bs[64][136];  // x tile bf16, pad+8

    // ---- stage x rows (64 batch rows at time t, 128 f32 each) -> bf16 LDS
    #pragma unroll
    for (int i = 0; i < 8; ++i) {
        int f4  = tid + i * 256;          // 2048 float4s
        int row = f4 >> 5, c4 = f4 & 31;
        float4 v = ((const float4*)(x + (size_t)(b0 + row) * (T_ * D_)
                                      + (size_t)t * D_))[c4];
        short4 s;
        s.x = (short)f2bf(v.x); s.y = (short)f2bf(v.y);
        s.z = (short)f2bf(v.z); s.w = (short)f2bf(v.w);
        *(short4*)&Bs[row][c4 * 4] = s;
    }

    // ---- A-frags: W_ih rows for this wave's 4 m-tiles, f32 -> bf16 regs
    v8s afr[4][4];          // [mtl][ks]
    float bias_r[4][4];     // [mtl][r]
    #pragma unroll
    for (int mtl = 0; mtl < 4; ++mtl) {
        const int gr = (w * 4 + mtl) * 16 + ml;     // A m-index = ml
        #pragma unroll
        for (int ks = 0; ks < 4; ++ks) {
            const float* p = W_ih + (size_t)gr * D_ + ks * 32 + q * 8;
            afr[mtl][ks] = pack8(((const float4*)p)[0], ((const float4*)p)[1]);
        }
        #pragma unroll
        for (int r = 0; r < 4; ++r) {
            const int gr2 = (w * 4 + mtl) * 16 + q * 4 + r;  // C row = q*4+r
            bias_r[mtl][r] = b_ih[gr2] + b_hh[gr2];
        }
    }
    __syncthreads();

    // ---- MFMA: acc[mtl][ntl] over 4 k-steps, bias in the init
    v4f acc[4][4];
    #pragma unroll
    for (int mtl = 0; mtl < 4; ++mtl)
        #pragma unroll
        for (int ntl = 0; ntl < 4; ++ntl)
            #pragma unroll
            for (int r = 0; r < 4; ++r)
                acc[mtl][ntl][r] = bias_r[mtl][r];

    #pragma unroll
    for (int ks = 0; ks < 4; ++ks)
        #pragma unroll
        for (int ntl = 0; ntl < 4; ++ntl) {
            v8s bf = *(const v8s*)&Bs[ntl * 16 + ml][ks * 32 + q * 8];
            #pragma unroll
            for (int mtl = 0; mtl < 4; ++mtl)
                acc[mtl][ntl] = __builtin_amdgcn_mfma_f32_16x16x32_bf16(
                    afr[mtl][ks], bf, acc[mtl][ntl], 0, 0, 0);
        }

    // ---- store: pack r0..r3 -> 8B, lane-contiguous 512B per instruction
    #pragma unroll
    for (int mtl = 0; mtl < 4; ++mtl) {
        const int gt = w * 4 + mtl;
        #pragma unroll
        for (int ntl = 0; ntl < 4; ++ntl) {
            const int bg = bbl * 4 + ntl;
            ushort4 p;
            p.x = f2bf(acc[mtl][ntl][0]); p.y = f2bf(acc[mtl][ntl][1]);
            p.z = f2bf(acc[mtl][ntl][2]); p.w = f2bf(acc[mtl][ntl][3]);
            xp[(((size_t)t * 64 + bg) * 16 + gt) * 64 + lane] = p;
        }
    }
}

// ---------------------------------------------------------------------------
// Phase 2 (transposed recurrence): 64 blocks x 256 thr; block bb owns batches
// bb*16..+15. Wave w owns hcols [16w,16w+16): gate-tiles gt = cls*4+w, so
// i/f/g/o for a (batch,hcol) pair land in the SAME lane's acc registers.
// Per step: 4 xp loads (acc init, prefetched 2 steps), 2 ds_read_b128 (h),
// 8 MFMA, 4-pair elementwise, 1 ds_write_b64 (packed bf16 h), 2 barriers.
// ---------------------------------------------------------------------------
__global__ __launch_bounds__(256, 1)
void recT_kernel(const ushort4* __restrict__ xp,   // [256][64][16][64]
                 const float* __restrict__ W_hh,   // [256,64]
                 const float* __restrict__ W1,     // [32,64]
                 const float* __restrict__ b1,     // [32]
                 const float* __restrict__ W2,     // [1,32]
                 const float* __restrict__ b2,     // [1]
                 float* __restrict__ out)          // [1024]
{
    const int bb   = blockIdx.x;
    const int tid  = threadIdx.x;
    const int w    = tid >> 6;
    const int lane = tid & 63;
    const int q    = lane >> 4;
    const int ml   = lane & 15;

    __shared__ __align__(16) unsigned short hbf[16][72];  // h bf16, pad+8
    __shared__ __align__(16) float hf[16][68];            // final h f32
    __shared__ __align__(16) float ys[16][36];            // head hidden

    // ---- preload W_hh A-frags [cls][ks]: A m-index = ml (gate row gt*16+ml)
    v8s whh[4][2];
    #pragma unroll
    for (int cls = 0; cls < 4; ++cls) {
        const int gr = (cls * 4 + w) * 16 + ml;
        #pragma unroll
        for (int ks = 0; ks < 2; ++ks) {
            const float* p = W_hh + (size_t)gr * H_ + ks * 32 + q * 8;
            whh[cls][ks] = pack8(((const float4*)p)[0], ((const float4*)p)[1]);
        }
    }

    // zero h (1152 shorts = 576 dwords)
    for (int i = tid; i < 576; i += 256) ((unsigned*)hbf)[i] = 0u;

    float c[4] = {0.f, 0.f, 0.f, 0.f};
    float hlast[4] = {0.f, 0.f, 0.f, 0.f};

    auto xpidx = [&](int t, int cls) -> size_t {
        return (((size_t)t * 64 + bb) * 16 + (cls * 4 + w)) * 64 + lane;
    };

    ushort4 pa[4], pb[4];
    #pragma unroll
    for (int cls = 0; cls < 4; ++cls) pa[cls] = xp[xpidx(0, cls)];
    #pragma unroll
    for (int cls = 0; cls < 4; ++cls) pb[cls] = xp[xpidx(1, cls)];

    __syncthreads();  // h zero-init visible

    auto step = [&](ushort4 (&buf)[4], int tpre) {
        // acc init from prefetched xp (bias already folded in phase 1)
        v4f acc[4];
        #pragma unroll
        for (int cls = 0; cls < 4; ++cls) {
            acc[cls][0] = bf2f(buf[cls].x);
            acc[cls][1] = bf2f(buf[cls].y);
            acc[cls][2] = bf2f(buf[cls].z);
            acc[cls][3] = bf2f(buf[cls].w);
        }
        // prefetch 2 steps ahead into the same buffer
        const int tp = tpre < 255 ? tpre : 255;
        #pragma unroll
        for (int cls = 0; cls < 4; ++cls) buf[cls] = xp[xpidx(tp, cls)];

        __syncthreads();  // prev h writes -> visible
        v8s h0 = *(const v8s*)&hbf[ml][q * 8];
        v8s h1 = *(const v8s*)&hbf[ml][32 + q * 8];
        #pragma unroll
        for (int cls = 0; cls < 4; ++cls) {
            acc[cls] = __builtin_amdgcn_mfma_f32_16x16x32_bf16(
                whh[cls][0], h0, acc[cls], 0, 0, 0);
            acc[cls] = __builtin_amdgcn_mfma_f32_16x16x32_bf16(
                whh[cls][1], h1, acc[cls], 0, 0, 0);
        }
        // elementwise: pairs (batch = bb*16+ml, hcol = 16w+q*4+r)
        #pragma unroll
        for (int r = 0; r < 4; ++r) {
            float gi = sigmoidf_(acc[0][r]);
            float gf = sigmoidf_(acc[1][r]);
            float gg = tanhf_(acc[2][r]);
            float go = sigmoidf_(acc[3][r]);
            c[r] = fmaf(gf, c[r], gi * gg);
            hlast[r] = go * tanhf_(c[r]);
        }
        __syncthreads();  // all reads of old h done
        ushort4 hp;
        hp.x = f2bf(hlast[0]); hp.y = f2bf(hlast[1]);
        hp.z = f2bf(hlast[2]); hp.w = f2bf(hlast[3]);
        *(ushort4*)&hbf[ml][w * 16 + q * 4] = hp;
    };

    for (int t = 0; t < T_; t += 2) {
        step(pa, t + 2);
        step(pb, t + 3);
    }
    // ---- head: final h is in hlast (f32, better than bf16 LDS copy)
    {
        float4 hv; hv.x = hlast[0]; hv.y = hlast[1]; hv.z = hlast[2]; hv.w = hlast[3];
        *(float4*)&hf[ml][w * 16 + q * 4] = hv;
    }
    __syncthreads();
    {
        const int bloc = tid & 15, jj = tid >> 4;
        #pragma unroll
        for (int j2 = 0; j2 < 2; ++j2) {
            const int j = jj + j2 * 16;
            float acc = b1[j];
            const float4* w1r = (const float4*)(W1 + (size_t)j * H_);
            #pragma unroll
            for (int k4 = 0; k4 < 16; ++k4) {
                float4 h4 = *(const float4*)&hf[bloc][k4 * 4];
                float4 w4 = w1r[k4];
                acc = fmaf(w4.x, h4.x, acc); acc = fmaf(w4.y, h4.y, acc);
                acc = fmaf(w4.z, h4.z, acc); acc = fmaf(w4.w, h4.w, acc);
            }
            ys[bloc][j] = fmaxf(acc, 0.0f);
        }
    }
    __syncthreads();
    if (tid < 16) {
        float a = b2[0];
        #pragma unroll
        for (int j = 0; j < 32; ++j) a = fmaf(W2[j], ys[tid][j], a);
        out[bb * 16 + tid] = sigmoidf_(a);
    }
}

// ---------------------------------------------------------------------------
// Fallback: round-1 fused fp32 kernel (used only if workspace too small).
// ---------------------------------------------------------------------------
__global__ __launch_bounds__(256, 2)
void lstm_fused_kernel(const float* __restrict__ x,
                       const float* __restrict__ W_ih,
                       const float* __restrict__ W_hh,
                       const float* __restrict__ b_ih,
                       const float* __restrict__ b_hh,
                       const float* __restrict__ W1,
                       const float* __restrict__ b1,
                       const float* __restrict__ W2,
                       const float* __restrict__ b2,
                       float* __restrict__ out)
{
    const int b = blockIdx.x;
    const int g = threadIdx.x;

    __shared__ __align__(16) float xs[D_];
    __shared__ __align__(16) float hs[H_];
    __shared__ __align__(16) float gates[G_];
    __shared__ __align__(16) float yss[32];

    float wih[D_];
    float whh[H_];
    {
        const float4* wr = (const float4*)(W_ih + (size_t)g * D_);
        #pragma unroll
        for (int k = 0; k < D_ / 4; ++k) {
            float4 v = wr[k];
            wih[4*k+0] = v.x; wih[4*k+1] = v.y;
            wih[4*k+2] = v.z; wih[4*k+3] = v.w;
        }
    }
    {
        const float4* wr = (const float4*)(W_hh + (size_t)g * H_);
        #pragma unroll
        for (int k = 0; k < H_ / 4; ++k) {
            float4 v = wr[k];
            whh[4*k+0] = v.x; whh[4*k+1] = v.y;
            whh[4*k+2] = v.z; whh[4*k+3] = v.w;
        }
    }
    const float bg  = b_ih[g] + b_hh[g];
    const int   cls = g >> 6;

    float c = 0.0f;
    if (g < H_) hs[g] = 0.0f;

    const float* __restrict__ xrow = x + (size_t)b * T_ * D_;

    for (int t = 0; t < T_; ++t) {
        if (g < D_) xs[g] = xrow[(size_t)t * D_ + g];
        __syncthreads();

        float a0 = bg, a1 = 0.f, a2 = 0.f, a3 = 0.f;
        const float4* xs4 = (const float4*)xs;
        #pragma unroll
        for (int k = 0; k < D_ / 4; ++k) {
            float4 v = xs4[k];
            a0 = fmaf(wih[4*k+0], v.x, a0);
            a1 = fmaf(wih[4*k+1], v.y, a1);
            a2 = fmaf(wih[4*k+2], v.z, a2);
            a3 = fmaf(wih[4*k+3], v.w, a3);
        }
        const float4* hs4 = (const float4*)hs;
        #pragma unroll
        for (int k = 0; k < H_ / 4; ++k) {
            float4 v = hs4[k];
            a0 = fmaf(whh[4*k+0], v.x, a0);
            a1 = fmaf(whh[4*k+1], v.y, a1);
            a2 = fmaf(whh[4*k+2], v.z, a2);
            a3 = fmaf(whh[4*k+3], v.w, a3);
        }
        float acc = (a0 + a1) + (a2 + a3);
        gates[g] = (cls == 2) ? tanhf_(acc) : sigmoidf_(acc);
        __syncthreads();

        if (g < H_) {
            float gi = gates[g];
            float gf = gates[H_ + g];
            float gg = gates[2 * H_ + g];
            float go = gates[3 * H_ + g];
            c = fmaf(gf, c, gi * gg);
            hs[g] = go * tanhf_(c);
        }
    }
    __syncthreads();

    if (g < 32) {
        float acc = b1[g];
        const float* w1r = W1 + g * H_;
        #pragma unroll
        for (int k = 0; k < H_; ++k) acc = fmaf(w1r[k], hs[k], acc);
        yss[g] = fmaxf(acc, 0.0f);
    }
    __syncthreads();
    if (g == 0) {
        float acc = b2[0];
        #pragma unroll
        for (int k = 0; k < 32; ++k) acc = fmaf(W2[k], yss[k], acc);
        out[b] = sigmoidf_(acc);
    }
}

extern "C" void kernel_launch(void* const* d_in, const int* in_sizes, int n_in,
                              void* d_out, int out_size, void* d_ws, size_t ws_size,
                              hipStream_t stream) {
    const float* x    = (const float*)d_in[0];
    const float* W_ih = (const float*)d_in[1];
    const float* W_hh = (const float*)d_in[2];
    const float* b_ih = (const float*)d_in[3];
    const float* b_hh = (const float*)d_in[4];
    const float* W1   = (const float*)d_in[5];
    const float* b1   = (const float*)d_in[6];
    const float* W2   = (const float*)d_in[7];
    const float* b2   = (const float*)d_in[8];
    float* out = (float*)d_out;

    const size_t xp_bytes = (size_t)M_ * G_ * sizeof(unsigned short);  // 134 MB

    if (ws_size >= xp_bytes) {
        ushort4* xp = (ushort4*)d_ws;
        xprojT_kernel<<<dim3(4096), dim3(256), 0, stream>>>(x, W_ih, b_ih, b_hh, xp);
        recT_kernel<<<dim3(64), dim3(256), 0, stream>>>(xp, W_hh, W1, b1, W2, b2, out);
    } else {
        lstm_fused_kernel<<<dim3(B_), dim3(256), 0, stream>>>(
            x, W_ih, W_hh, b_ih, b_hh, W1, b1, W2, b2, out);
    }
}